// Round 6
// baseline (726.146 us; speedup 1.0000x reference)
//
#include <hip/hip_runtime.h>
#include <math.h>

// infoFSM mask-scorer MLP — Round 8: pure-bf16 MFMA + wide band + exact fix.
//
// R7 post-mortem: MfmaUtil 28.5% x 260us = 74us MFMA-busy = the bf16x3 MFMA
// floor itself. The pipe was never starved; the other 186us is VALU (78us:
// hi/lo splits, 3x epilogues) + serialized memory phases at 1 block/CU.
// Error audit (input N(0,1), sigma_w=0.05, layer gain ~0.5-0.7): pure-bf16
// rounding of input+weights+activations -> v-error RMS ~1.3e-4. BAND=1e-2
// (77x RMS) keeps out-of-band decisions exact; in-band (~3%) recomputed
// exactly in fp32 by pass C. So drop ALL hi/lo terms:
//  - 1 MFMA per product: MFMA floor 74 -> 25us
//  - LDS 64KB at TM=64 -> 2 blocks/CU (cross-block phase overlap) AND
//    halved weight L2 traffic at the same time
//  - staging/epilogue VALU ~halves (single cvt, no lo-split)
// Structure: 8-barrier overlay A->X1->X2->X3 in one 64KB region.

namespace {

constexpr int R_ROWS = 128 * 512;   // 65536
constexpr int D0 = 512, D1 = 512, D2 = 256, D3 = 128;
constexpr int TM = 64;              // rows per block (pass B)
constexpr int NT = 512;             // 8 waves

typedef __attribute__((ext_vector_type(8)))  short          vshort8;
typedef __attribute__((ext_vector_type(4)))  unsigned short vus4;
typedef __attribute__((ext_vector_type(8)))  unsigned short vus8;
typedef __attribute__((ext_vector_type(16))) float          vf16;
typedef __attribute__((ext_vector_type(4)))  float          vf4;

// ---------------- helpers ----------------
__device__ __forceinline__ unsigned short f32_to_bf16(float x) {
    unsigned int b = __float_as_uint(x);
    b += 0x7FFFu + ((b >> 16) & 1u);          // RNE (inputs finite)
    return (unsigned short)(b >> 16);
}
__device__ __forceinline__ float gelu_exact(float x) {
    return 0.5f * x * (1.0f + erff(x * 0.70710678118654752440f));
}
// A&S 7.1.26 erf: |abs err| <= 1.5e-7 — far below bf16 path error.
__device__ __forceinline__ float gelu_fast(float x) {
    const float s = fabsf(x) * 0.70710678118654752440f;
    const float t = __builtin_amdgcn_rcpf(fmaf(0.3275911f, s, 1.0f));
    float p = fmaf(1.061405429f, t, -1.453152027f);
    p = fmaf(p, t, 1.421413741f);
    p = fmaf(p, t, -0.284496736f);
    p = fmaf(p, t, 0.254829592f);
    p *= t;
    const float e = __builtin_amdgcn_exp2f(s * s * -1.44269504088896341f);
    float er = fmaf(-p, e, 1.0f);             // erf(|x|/sqrt2)
    er = copysignf(er, x);
    return 0.5f * x * (1.0f + er);
}
__device__ __forceinline__ vf16 vzero16() {
    vf16 v;
    #pragma unroll
    for (int i = 0; i < 16; ++i) v[i] = 0.0f;
    return v;
}
__device__ __forceinline__ vf4 vzero4() {
    vf4 v;
    #pragma unroll
    for (int i = 0; i < 4; ++i) v[i] = 0.0f;
    return v;
}

// LDS activation tiles: [row][k] bf16, XOR-swizzle bits 4..6.
__device__ __forceinline__ int swz_off(int row, int colElem, int pitchB) {
    return (row * pitchB + colElem * 2) ^ ((row & 7) << 4);
}
// 32x32 A-fragment read: row = row0 + lane&31, k = k0 + (lane>>5)*8
__device__ __forceinline__ vshort8 ld_act32(const char* base, int lane, int pitchB,
                                            int row0, int k0) {
    const int row = row0 + (lane & 31);
    const int k = k0 + ((lane >> 5) << 3);
    return *(const vshort8*)(base + swz_off(row, k, pitchB));
}
// 16x16 A-fragment read: row = row0 + lane&15, k = k0 + (lane>>4)*8
__device__ __forceinline__ vshort8 ld_act16(const char* base, int lane, int pitchB,
                                            int row0, int k0) {
    const int row = row0 + (lane & 15);
    const int k = k0 + ((lane >> 4) << 3);
    return *(const vshort8*)(base + swz_off(row, k, pitchB));
}
// packed weight fragment (hi-only): P + blk*1024B + lane*16B
__device__ __forceinline__ vshort8 ld_pack(const unsigned short* __restrict__ P,
                                           int blk, int lane) {
    return *(const vshort8*)((const char*)P + (((size_t)blk) << 10) + (lane << 4));
}
__device__ __forceinline__ void st_hi(char* base, int row, int col, int pitchB, float x) {
    *(unsigned short*)(base + swz_off(row, col, pitchB)) = f32_to_bf16(x);
}

#define MFMA32(a, b, c) __builtin_amdgcn_mfma_f32_32x32x16_bf16((a), (b), (c), 0, 0, 0)
#define MFMA16(a, b, c) __builtin_amdgcn_mfma_f32_16x16x32_bf16((a), (b), (c), 0, 0, 0)

constexpr float BAND = 1e-2f;   // on v = prob*prev_m; ~77x RMS bf16-path error

// ---------------- pass A: pack bf16 weights into fragment order -------------
// P1: GEMM1 (32x32x16): blk = nt*32+ks, nt=0..15; lane l -> W_L[nt*32+(l&31)][ks*16+(l>>5)*8+j]
// P2: GEMM2: blk = nt*32+ks, nt=0..7 (W_l1)
// P3: GEMM3 (16x16x32): blk = nt*8+ks, nt=0..7; lane l -> W_l2[nt*16+(l&15)][ks*32+(l>>4)*8+j]
__global__ __launch_bounds__(256) void pack_weights(
    const float* __restrict__ W_L, const float* __restrict__ W_l1,
    const float* __restrict__ W_l2,
    unsigned short* __restrict__ P1, unsigned short* __restrict__ P2,
    unsigned short* __restrict__ P3)
{
    const int g = blockIdx.x * 256 + threadIdx.x;   // 53248 threads total
    const float* src;
    unsigned short* dst;
    int e, k, K, blk, lane;
    if (g < 32768) {
        lane = g & 63;
        const int ks = (g >> 6) & 31, nt = g >> 11;
        src = W_L; K = 512; dst = P1;
        e = nt * 32 + (lane & 31);
        k = ks * 16 + ((lane >> 5) << 3);
        blk = nt * 32 + ks;
    } else if (g < 49152) {
        const int h = g - 32768;
        lane = h & 63;
        const int ks = (h >> 6) & 31, nt = h >> 11;
        src = W_l1; K = 512; dst = P2;
        e = nt * 32 + (lane & 31);
        k = ks * 16 + ((lane >> 5) << 3);
        blk = nt * 32 + ks;
    } else {
        const int h = g - 49152;
        lane = h & 63;
        const int ks = (h >> 6) & 7, nt = h >> 9;
        src = W_l2; K = 256; dst = P3;
        e = nt * 16 + (lane & 15);
        k = ks * 32 + ((lane >> 4) << 3);
        blk = nt * 8 + ks;
    }
    const float4 v0 = *(const float4*)&src[(size_t)e * K + k];
    const float4 v1 = *(const float4*)&src[(size_t)e * K + k + 4];
    const float xs[8] = {v0.x, v0.y, v0.z, v0.w, v1.x, v1.y, v1.z, v1.w};
    vus8 hv;
    #pragma unroll
    for (int j = 0; j < 8; ++j) hv[j] = f32_to_bf16(xs[j]);
    *(vus8*)(dst + ((size_t)blk << 9) + lane * 8) = hv;   // 512 shorts per blk
}

// ---------------- pass B: fused bf16 MFMA MLP, TM=64, 64KB LDS --------------
// LDS overlay (bytes), one 64KB region + sM:
//   stage A:  A  [0,64K)  bf16 [64][512] pitch 1024
//   GEMM1 ep: X1 [0,64K)  bf16 [64][512] pitch 1024  (A dead, B2a)
//   GEMM2 ep: X2 [0,32K)  bf16 [64][256] pitch 512   (X1 dead, B3a)
//   GEMM3 ep: X3 [0,33792) f32 [64][132]             (X2 dead, B4a)
//   sM at [65536, 65792)
constexpr int SMEM_BYTES = 65536 + 256;

__global__ __launch_bounds__(NT, 4) void mlp_mfma(
    const float* __restrict__ input, const float* __restrict__ prev_m,
    const float* __restrict__ W_l3,
    const unsigned short* __restrict__ P1, const unsigned short* __restrict__ P2,
    const unsigned short* __restrict__ P3,
    float* __restrict__ out, float* __restrict__ mask_out, float* __restrict__ currm_out,
    unsigned int* __restrict__ ctr, int* __restrict__ list)
{
    __shared__ __attribute__((aligned(16))) char smem[SMEM_BYTES];
    char* A   = smem;                         // then X1, then X2 (overlaid)
    float* sX3 = (float*)smem;                // [64][132] f32 (over X2, post-B4a)
    float* sM  = (float*)(smem + 65536);      // [64]

    const int tid  = threadIdx.x;
    const int lane = tid & 63;
    const int wid  = tid >> 6;
    const int row0 = blockIdx.x * TM;

    // ---- stage A: 64 input rows -> bf16, swizzled ----
    #pragma unroll
    for (int i = 0; i < 16; ++i) {
        const int c  = i * NT + tid;           // 0..8191 float4-chunks
        const int r  = c >> 7;                 // 0..63
        const int kq = (c & 127) << 2;
        const float4 v = *(const float4*)&input[(size_t)(row0 + r) * D0 + kq];
        vus4 hv = {f32_to_bf16(v.x), f32_to_bf16(v.y),
                   f32_to_bf16(v.z), f32_to_bf16(v.w)};
        const int off = (r * 1024 + kq * 2) ^ ((r & 7) << 4);   // 8B-aligned
        *(vus4*)(A + off) = hv;
    }
    __syncthreads();   // B1: A staged

    // ---- GEMM1: X1 = gelu(A @ W_L^T), 64x512, K=512, 32x32x16 ----
    vf16 g1a00, g1a01, g1a10, g1a11;   // [m-tile][n-tile]
    {
        const int nt0 = wid * 2;               // wave owns n-tiles nt0, nt0+1
        vf16 a00 = vzero16(), a01 = vzero16(), a10 = vzero16(), a11 = vzero16();
        #pragma unroll 4
        for (int ks = 0; ks < 32; ++ks) {
            const int k0 = ks * 16;
            vshort8 ah0 = ld_act32(A, lane, 1024, 0,  k0);
            vshort8 ah1 = ld_act32(A, lane, 1024, 32, k0);
            vshort8 b0  = ld_pack(P1, nt0 * 32 + ks, lane);
            vshort8 b1  = ld_pack(P1, (nt0 + 1) * 32 + ks, lane);
            a00 = MFMA32(ah0, b0, a00);
            a01 = MFMA32(ah0, b1, a01);
            a10 = MFMA32(ah1, b0, a10);
            a11 = MFMA32(ah1, b1, a11);
        }
        g1a00 = a00; g1a01 = a01; g1a10 = a10; g1a11 = a11;
    }
    __syncthreads();   // B2a: all waves done reading A
    {
        const int e0 = wid * 64;
        #pragma unroll
        for (int r = 0; r < 16; ++r) {
            const int rr = (r & 3) + 8 * (r >> 2) + 4 * (lane >> 5);
            st_hi(A, rr,      e0 + (lane & 31),      1024, gelu_fast(g1a00[r]));
            st_hi(A, rr,      e0 + 32 + (lane & 31), 1024, gelu_fast(g1a01[r]));
            st_hi(A, rr + 32, e0 + (lane & 31),      1024, gelu_fast(g1a10[r]));
            st_hi(A, rr + 32, e0 + 32 + (lane & 31), 1024, gelu_fast(g1a11[r]));
        }
    }
    __syncthreads();   // B2b: X1 ready (in A's region)

    // ---- GEMM2: X2 = gelu(X1 @ W_l1^T), 64x256, K=512, 32x32x16 ----
    // 4 acc chains (even/odd ks) so no acc is reused within <4 MFMA issues.
    vf16 g2a0, g2a1;
    {
        vf16 c0A = vzero16(), c1A = vzero16();
        vf16 c0B = vzero16(), c1B = vzero16();
        #pragma unroll 2
        for (int ks = 0; ks < 32; ks += 2) {
            {
                const int k0 = ks * 16;
                vshort8 ah0 = ld_act32(A, lane, 1024, 0,  k0);
                vshort8 ah1 = ld_act32(A, lane, 1024, 32, k0);
                vshort8 b   = ld_pack(P2, wid * 32 + ks, lane);
                c0A = MFMA32(ah0, b, c0A);
                c1A = MFMA32(ah1, b, c1A);
            }
            {
                const int k0 = ks * 16 + 16;
                vshort8 ah0 = ld_act32(A, lane, 1024, 0,  k0);
                vshort8 ah1 = ld_act32(A, lane, 1024, 32, k0);
                vshort8 b   = ld_pack(P2, wid * 32 + ks + 1, lane);
                c0B = MFMA32(ah0, b, c0B);
                c1B = MFMA32(ah1, b, c1B);
            }
        }
        g2a0 = c0A + c0B; g2a1 = c1A + c1B;
    }
    __syncthreads();   // B3a: all waves done reading X1
    {
        const int e0 = wid * 32;
        #pragma unroll
        for (int r = 0; r < 16; ++r) {
            const int rr = (r & 3) + 8 * (r >> 2) + 4 * (lane >> 5);
            st_hi(A, rr,      e0 + (lane & 31), 512, gelu_fast(g2a0[r]));
            st_hi(A, rr + 32, e0 + (lane & 31), 512, gelu_fast(g2a1[r]));
        }
    }
    __syncthreads();   // B3b: X2 ready (in [0,32K))

    // ---- GEMM3: X3 = gelu(X2 @ W_l2^T), 64x128, K=256, 16x16x32 ----
    {
        const int e0 = wid * 16;               // wave owns n-tile wid
        vf4 ac[4];                             // m-tiles: rows 16*mt..16*mt+15
        #pragma unroll
        for (int mt = 0; mt < 4; ++mt) ac[mt] = vzero4();
        #pragma unroll 2
        for (int ks = 0; ks < 8; ++ks) {
            const int k0 = ks * 32;
            vshort8 b = ld_pack(P3, wid * 8 + ks, lane);
            #pragma unroll
            for (int mt = 0; mt < 4; ++mt) {
                vshort8 ah = ld_act16(A, lane, 512, mt * 16, k0);
                ac[mt] = MFMA16(ah, b, ac[mt]);
            }
        }
        __syncthreads();   // B4a: all waves done reading X2
        #pragma unroll
        for (int mt = 0; mt < 4; ++mt)
            #pragma unroll
            for (int r = 0; r < 4; ++r) {
                const int rr = mt * 16 + ((lane >> 4) << 2) + r;
                sX3[rr * 132 + e0 + (lane & 15)] = gelu_fast(ac[mt][r]);
            }
    }
    __syncthreads();   // B4b: X3 ready

    // ---- layer4 (fp32) + decision + flag: 64 rows x 8 lanes ----
    {
        const int row = tid >> 3;
        const int j   = tid & 7;
        float p = 0.0f;
        #pragma unroll
        for (int t = 0; t < 16; ++t)
            p = fmaf(sX3[row * 132 + j + 8 * t], W_l3[j + 8 * t], p);
        p += __shfl_down(p, 4, 8);
        p += __shfl_down(p, 2, 8);
        p += __shfl_down(p, 1, 8);
        if (j == 0) {
            const float prob = 1.0f / (1.0f + expf(-p));
            const float v    = prob * prev_m[row0 + row];
            const float st   = (v > 0.5f) ? 1.0f : 0.0f;
            const float cm   = st + 1e-10f;
            sM[row] = cm;
            mask_out[row0 + row]  = st;
            currm_out[row0 + row] = cm;
            if (fabsf(v - 0.5f) < BAND) {
                const unsigned int slot = atomicAdd(ctr, 1u);
                list[slot] = row0 + row;
            }
        }
    }
    __syncthreads();   // B5: sM ready

    // ---- epilogue: out = input * curr_m (re-read; L3-resident) ----
    #pragma unroll
    for (int it = 0; it < 16; ++it) {
        const int c = it * NT + tid;           // 8192 float4 = 64 rows x 128
        const int r = c >> 7;
        const int q = (c & 127) << 2;
        const float m = sM[r];
        const float4 v = *(const float4*)&input[(size_t)(row0 + r) * D0 + q];
        float4 o;
        o.x = v.x * m; o.y = v.y * m; o.z = v.z * m; o.w = v.w * m;
        *(float4*)&out[(size_t)(row0 + r) * D0 + q] = o;
    }
}

// ---------------- pass C: exact fp32 recompute of flagged rows ----------------
__global__ __launch_bounds__(256) void fix_rows(
    const float* __restrict__ input, const float* __restrict__ prev_m,
    const float* __restrict__ W_L, const float* __restrict__ W_l1,
    const float* __restrict__ W_l2, const float* __restrict__ W_l3,
    const unsigned int* __restrict__ ctr, const int* __restrict__ list,
    float* __restrict__ out, float* __restrict__ mask_out, float* __restrict__ currm_out)
{
    __shared__ float sx[8][512];
    __shared__ float s1[8][512];
    __shared__ float s2[8][256];
    __shared__ float s3[8][128];
    __shared__ float scm[8];
    const int tid = threadIdx.x;
    const int n = (int)*ctr;

    for (int base = blockIdx.x * 8; base < n; base += gridDim.x * 8) {
        int cnt = n - base;
        if (cnt > 8) cnt = 8;
        __syncthreads();                       // protect prev iteration LDS
        #pragma unroll
        for (int g = 0; g < 8; ++g) {
            if (g < cnt) {
                const int row = list[base + g];
                for (int j = tid; j < 512; j += 256)
                    sx[g][j] = input[(size_t)row * 512 + j];
            } else {
                for (int j = tid; j < 512; j += 256) sx[g][j] = 0.0f;
            }
        }
        __syncthreads();
        #pragma unroll
        for (int half = 0; half < 2; ++half) {
            const int e = tid + half * 256;
            const float4* wr = (const float4*)&W_L[e * 512];
            float a[8];
            #pragma unroll
            for (int g = 0; g < 8; ++g) a[g] = 0.0f;
            for (int kq = 0; kq < 128; ++kq) {
                const float4 w = wr[kq];
                #pragma unroll
                for (int g = 0; g < 8; ++g) {
                    const float4 xv = *(const float4*)&sx[g][kq * 4];
                    a[g] = fmaf(xv.x, w.x, a[g]); a[g] = fmaf(xv.y, w.y, a[g]);
                    a[g] = fmaf(xv.z, w.z, a[g]); a[g] = fmaf(xv.w, w.w, a[g]);
                }
            }
            #pragma unroll
            for (int g = 0; g < 8; ++g) s1[g][e] = gelu_exact(a[g]);
        }
        __syncthreads();
        {
            const int e = tid;
            const float4* wr = (const float4*)&W_l1[e * 512];
            float a[8];
            #pragma unroll
            for (int g = 0; g < 8; ++g) a[g] = 0.0f;
            for (int kq = 0; kq < 128; ++kq) {
                const float4 w = wr[kq];
                #pragma unroll
                for (int g = 0; g < 8; ++g) {
                    const float4 xv = *(const float4*)&s1[g][kq * 4];
                    a[g] = fmaf(xv.x, w.x, a[g]); a[g] = fmaf(xv.y, w.y, a[g]);
                    a[g] = fmaf(xv.z, w.z, a[g]); a[g] = fmaf(xv.w, w.w, a[g]);
                }
            }
            #pragma unroll
            for (int g = 0; g < 8; ++g) s2[g][e] = gelu_exact(a[g]);
        }
        __syncthreads();
        if (tid < 128) {
            const int e = tid;
            const float4* wr = (const float4*)&W_l2[e * 256];
            float a[8];
            #pragma unroll
            for (int g = 0; g < 8; ++g) a[g] = 0.0f;
            for (int kq = 0; kq < 64; ++kq) {
                const float4 w = wr[kq];
                #pragma unroll
                for (int g = 0; g < 8; ++g) {
                    const float4 xv = *(const float4*)&s2[g][kq * 4];
                    a[g] = fmaf(xv.x, w.x, a[g]); a[g] = fmaf(xv.y, w.y, a[g]);
                    a[g] = fmaf(xv.z, w.z, a[g]); a[g] = fmaf(xv.w, w.w, a[g]);
                }
            }
            #pragma unroll
            for (int g = 0; g < 8; ++g) s3[g][e] = gelu_exact(a[g]);
        }
        __syncthreads();
        if (tid < 128) {
            const int g = tid >> 4, j = tid & 15;
            float p = 0.0f;
            #pragma unroll
            for (int t = 0; t < 8; ++t)
                p = fmaf(s3[g][j + 16 * t], W_l3[j + 16 * t], p);
            #pragma unroll
            for (int off = 8; off > 0; off >>= 1)
                p += __shfl_down(p, off, 16);
            if (j == 0 && g < cnt) {
                const int row = list[base + g];
                const float prob = 1.0f / (1.0f + expf(-p));
                const float v    = prob * prev_m[row];
                const float st   = (v > 0.5f) ? 1.0f : 0.0f;
                const float cm   = st + 1e-10f;
                mask_out[row]  = st;
                currm_out[row] = cm;
                scm[g] = cm;
            }
        }
        __syncthreads();
        for (int idx = tid; idx < cnt * 128; idx += 256) {
            const int g = idx >> 7;
            const int q = (idx & 127) << 2;
            const int row = list[base + g];
            const float cm = scm[g];
            const float4 v = *(const float4*)&input[(size_t)row * 512 + q];
            float4 o;
            o.x = v.x * cm; o.y = v.y * cm; o.z = v.z * cm; o.w = v.w * cm;
            *(float4*)&out[(size_t)row * 512 + q] = o;
        }
    }
}

}  // namespace

extern "C" void kernel_launch(void* const* d_in, const int* in_sizes, int n_in,
                              void* d_out, int out_size, void* d_ws, size_t ws_size,
                              hipStream_t stream) {
    const float* input  = (const float*)d_in[0];
    // d_in[1] = attention_mask: unused by the reference computation
    const float* prev_m = (const float*)d_in[2];
    const float* W_L    = (const float*)d_in[3];
    const float* W_l1   = (const float*)d_in[4];
    const float* W_l2   = (const float*)d_in[5];
    const float* W_l3   = (const float*)d_in[6];

    float* out_p   = (float*)d_out;                  // [R, 512]
    float* mask_p  = out_p + (size_t)R_ROWS * D0;    // [R]
    float* currm_p = mask_p + R_ROWS;                // [R]

    // workspace (bytes): ctr @0, list @1024 (256KB), packed bf16 weights after
    char* ws = (char*)d_ws;
    unsigned int* ctr = (unsigned int*)ws;
    int* list = (int*)(ws + 1024);
    unsigned short* P1 = (unsigned short*)(ws + 263168);    // 512 KB
    unsigned short* P2 = (unsigned short*)(ws + 787456);    // 256 KB
    unsigned short* P3 = (unsigned short*)(ws + 1049600);   // 64 KB
    // total ws use: 1115136 bytes

    hipMemsetAsync(ctr, 0, sizeof(unsigned int), stream);
    pack_weights<<<208, 256, 0, stream>>>(W_L, W_l1, W_l2, P1, P2, P3);
    mlp_mfma<<<R_ROWS / TM, NT, 0, stream>>>(input, prev_m, W_l3,
                                             P1, P2, P3,
                                             out_p, mask_p, currm_p, ctr, list);
    fix_rows<<<1024, 256, 0, stream>>>(input, prev_m, W_L, W_l1, W_l2, W_l3,
                                       ctr, list, out_p, mask_p, currm_p);
}

// Round 7
// 274.544 us; speedup vs baseline: 2.6449x; 2.6449x over previous
//
#include <hip/hip_runtime.h>
#include <math.h>

// infoFSM mask-scorer MLP — Round 9: fp16 MFMA pass B + throughput fix pass.
//
// R8 post-mortem: mlp_mfma dropped to ~120us (pure-16bit path works) but
// BAND=1e-2 flagged ~20-40% of rows (logit sigma~0.1 -> prob concentrated
// near 0.5; band must be sized to ERROR, flagged count follows DATA) and the
// old 8-rows/iter latency-exposed fix ran 600us. R9:
//  - pass B in fp16 (mfma_f32_*_f16, same rate as bf16; 10-bit mantissa ->
//    v-error RMS ~9e-5). BAND=2e-3 = 22sigma (bf16@1e-2~28sigma and
//    bf16x3@1e-3~100sigma both verified absmax=0). Flagged ~3-6k rows.
//  - fix_rows rebuilt: 16 rows/iter, 512 thr (L1 e=tid exactly 512; L2/L3
//    split rows across thread groups), 88KB LDS, broadcast reads, unroll-2
//    weight prefetch -> compute-bound ~20us/iter, depth 1.

namespace {

constexpr int R_ROWS = 128 * 512;   // 65536
constexpr int D0 = 512, D1 = 512, D2 = 256, D3 = 128;
constexpr int TM = 64;              // rows per block (pass B)
constexpr int NT = 512;             // 8 waves

typedef _Float16 vhalf8 __attribute__((ext_vector_type(8)));
typedef _Float16 vhalf4 __attribute__((ext_vector_type(4)));
typedef __attribute__((ext_vector_type(16))) float vf16;
typedef __attribute__((ext_vector_type(4)))  float vf4;

// ---------------- helpers ----------------
__device__ __forceinline__ float gelu_exact(float x) {
    return 0.5f * x * (1.0f + erff(x * 0.70710678118654752440f));
}
// A&S 7.1.26 erf: |abs err| <= 1.5e-7 — far below fp16 path error.
__device__ __forceinline__ float gelu_fast(float x) {
    const float s = fabsf(x) * 0.70710678118654752440f;
    const float t = __builtin_amdgcn_rcpf(fmaf(0.3275911f, s, 1.0f));
    float p = fmaf(1.061405429f, t, -1.453152027f);
    p = fmaf(p, t, 1.421413741f);
    p = fmaf(p, t, -0.284496736f);
    p = fmaf(p, t, 0.254829592f);
    p *= t;
    const float e = __builtin_amdgcn_exp2f(s * s * -1.44269504088896341f);
    float er = fmaf(-p, e, 1.0f);             // erf(|x|/sqrt2)
    er = copysignf(er, x);
    return 0.5f * x * (1.0f + er);
}
__device__ __forceinline__ vf16 vzero16() {
    vf16 v;
    #pragma unroll
    for (int i = 0; i < 16; ++i) v[i] = 0.0f;
    return v;
}
__device__ __forceinline__ vf4 vzero4() {
    vf4 v;
    #pragma unroll
    for (int i = 0; i < 4; ++i) v[i] = 0.0f;
    return v;
}

// LDS activation tiles: [row][k] fp16, XOR-swizzle bits 4..6.
__device__ __forceinline__ int swz_off(int row, int colElem, int pitchB) {
    return (row * pitchB + colElem * 2) ^ ((row & 7) << 4);
}
// 32x32 A-fragment read: row = row0 + lane&31, k = k0 + (lane>>5)*8
__device__ __forceinline__ vhalf8 ld_act32(const char* base, int lane, int pitchB,
                                           int row0, int k0) {
    const int row = row0 + (lane & 31);
    const int k = k0 + ((lane >> 5) << 3);
    return *(const vhalf8*)(base + swz_off(row, k, pitchB));
}
// 16x16 A-fragment read: row = row0 + lane&15, k = k0 + (lane>>4)*8
__device__ __forceinline__ vhalf8 ld_act16(const char* base, int lane, int pitchB,
                                           int row0, int k0) {
    const int row = row0 + (lane & 15);
    const int k = k0 + ((lane >> 4) << 3);
    return *(const vhalf8*)(base + swz_off(row, k, pitchB));
}
// packed weight fragment: P + blk*1024B + lane*16B
__device__ __forceinline__ vhalf8 ld_pack(const char* __restrict__ P,
                                          int blk, int lane) {
    return *(const vhalf8*)(P + (((size_t)blk) << 10) + (lane << 4));
}
__device__ __forceinline__ void st_hi(char* base, int row, int col, int pitchB, float x) {
    *(_Float16*)(base + swz_off(row, col, pitchB)) = (_Float16)x;
}

#define MFMA32(a, b, c) __builtin_amdgcn_mfma_f32_32x32x16_f16((a), (b), (c), 0, 0, 0)
#define MFMA16(a, b, c) __builtin_amdgcn_mfma_f32_16x16x32_f16((a), (b), (c), 0, 0, 0)

constexpr float BAND = 2e-3f;   // on v = prob*prev_m; ~22x RMS fp16-path error

// ---------------- pass A: pack fp16 weights into fragment order -------------
// P1: GEMM1 (32x32x16): blk=nt*32+ks, nt=0..15; lane l -> W_L[nt*32+(l&31)][ks*16+(l>>5)*8+j]
// P2: GEMM2: blk=nt*32+ks, nt=0..7 (W_l1)
// P3: GEMM3 (16x16x32): blk=nt*8+ks, nt=0..7; lane l -> W_l2[nt*16+(l&15)][ks*32+(l>>4)*8+j]
__global__ __launch_bounds__(256) void pack_weights(
    const float* __restrict__ W_L, const float* __restrict__ W_l1,
    const float* __restrict__ W_l2,
    char* __restrict__ P1, char* __restrict__ P2, char* __restrict__ P3)
{
    const int g = blockIdx.x * 256 + threadIdx.x;   // 53248 threads total
    const float* src;
    char* dst;
    int e, k, K, blk, lane;
    if (g < 32768) {
        lane = g & 63;
        const int ks = (g >> 6) & 31, nt = g >> 11;
        src = W_L; K = 512; dst = P1;
        e = nt * 32 + (lane & 31);
        k = ks * 16 + ((lane >> 5) << 3);
        blk = nt * 32 + ks;
    } else if (g < 49152) {
        const int h = g - 32768;
        lane = h & 63;
        const int ks = (h >> 6) & 31, nt = h >> 11;
        src = W_l1; K = 512; dst = P2;
        e = nt * 32 + (lane & 31);
        k = ks * 16 + ((lane >> 5) << 3);
        blk = nt * 32 + ks;
    } else {
        const int h = g - 49152;
        lane = h & 63;
        const int ks = (h >> 6) & 7, nt = h >> 9;
        src = W_l2; K = 256; dst = P3;
        e = nt * 16 + (lane & 15);
        k = ks * 32 + ((lane >> 4) << 3);
        blk = nt * 8 + ks;
    }
    const float4 v0 = *(const float4*)&src[(size_t)e * K + k];
    const float4 v1 = *(const float4*)&src[(size_t)e * K + k + 4];
    const float xs[8] = {v0.x, v0.y, v0.z, v0.w, v1.x, v1.y, v1.z, v1.w};
    vhalf8 hv;
    #pragma unroll
    for (int j = 0; j < 8; ++j) hv[j] = (_Float16)xs[j];
    *(vhalf8*)(dst + (((size_t)blk) << 10) + lane * 16) = hv;
}

// ---------------- pass B: fused fp16 MFMA MLP, TM=64, 64KB LDS --------------
// LDS overlay (bytes), one 64KB region + sM:
//   stage A:  A  [0,64K)  f16 [64][512] pitch 1024
//   GEMM1 ep: X1 [0,64K)  f16 [64][512] pitch 1024  (A dead, B2a)
//   GEMM2 ep: X2 [0,32K)  f16 [64][256] pitch 512   (X1 dead, B3a)
//   GEMM3 ep: X3 [0,33792) f32 [64][132]            (X2 dead, B4a)
//   sM at [65536, 65792)
constexpr int SMEM_BYTES = 65536 + 256;

__global__ __launch_bounds__(NT, 4) void mlp_mfma(
    const float* __restrict__ input, const float* __restrict__ prev_m,
    const float* __restrict__ W_l3,
    const char* __restrict__ P1, const char* __restrict__ P2,
    const char* __restrict__ P3,
    float* __restrict__ out, float* __restrict__ mask_out, float* __restrict__ currm_out,
    unsigned int* __restrict__ ctr, int* __restrict__ list)
{
    __shared__ __attribute__((aligned(16))) char smem[SMEM_BYTES];
    char* A   = smem;                         // then X1, then X2 (overlaid)
    float* sX3 = (float*)smem;                // [64][132] f32 (over X2, post-B4a)
    float* sM  = (float*)(smem + 65536);      // [64]

    const int tid  = threadIdx.x;
    const int lane = tid & 63;
    const int wid  = tid >> 6;
    const int row0 = blockIdx.x * TM;

    // ---- stage A: 64 input rows -> fp16, swizzled ----
    #pragma unroll
    for (int i = 0; i < 16; ++i) {
        const int c  = i * NT + tid;           // 0..8191 float4-chunks
        const int r  = c >> 7;                 // 0..63
        const int kq = (c & 127) << 2;
        const float4 v = *(const float4*)&input[(size_t)(row0 + r) * D0 + kq];
        vhalf4 hv = {(_Float16)v.x, (_Float16)v.y, (_Float16)v.z, (_Float16)v.w};
        const int off = (r * 1024 + kq * 2) ^ ((r & 7) << 4);   // 8B-aligned
        *(vhalf4*)(A + off) = hv;
    }
    __syncthreads();   // B1: A staged

    // ---- GEMM1: X1 = gelu(A @ W_L^T), 64x512, K=512, 32x32x16 ----
    vf16 g1a00, g1a01, g1a10, g1a11;   // [m-tile][n-tile]
    {
        const int nt0 = wid * 2;               // wave owns n-tiles nt0, nt0+1
        vf16 a00 = vzero16(), a01 = vzero16(), a10 = vzero16(), a11 = vzero16();
        #pragma unroll 4
        for (int ks = 0; ks < 32; ++ks) {
            const int k0 = ks * 16;
            vhalf8 ah0 = ld_act32(A, lane, 1024, 0,  k0);
            vhalf8 ah1 = ld_act32(A, lane, 1024, 32, k0);
            vhalf8 b0  = ld_pack(P1, nt0 * 32 + ks, lane);
            vhalf8 b1  = ld_pack(P1, (nt0 + 1) * 32 + ks, lane);
            a00 = MFMA32(ah0, b0, a00);
            a01 = MFMA32(ah0, b1, a01);
            a10 = MFMA32(ah1, b0, a10);
            a11 = MFMA32(ah1, b1, a11);
        }
        g1a00 = a00; g1a01 = a01; g1a10 = a10; g1a11 = a11;
    }
    __syncthreads();   // B2a: all waves done reading A
    {
        const int e0 = wid * 64;
        #pragma unroll
        for (int r = 0; r < 16; ++r) {
            const int rr = (r & 3) + 8 * (r >> 2) + 4 * (lane >> 5);
            st_hi(A, rr,      e0 + (lane & 31),      1024, gelu_fast(g1a00[r]));
            st_hi(A, rr,      e0 + 32 + (lane & 31), 1024, gelu_fast(g1a01[r]));
            st_hi(A, rr + 32, e0 + (lane & 31),      1024, gelu_fast(g1a10[r]));
            st_hi(A, rr + 32, e0 + 32 + (lane & 31), 1024, gelu_fast(g1a11[r]));
        }
    }
    __syncthreads();   // B2b: X1 ready (in A's region)

    // ---- GEMM2: X2 = gelu(X1 @ W_l1^T), 64x256, K=512, 32x32x16 ----
    vf16 g2a0, g2a1;
    {
        vf16 c0A = vzero16(), c1A = vzero16();
        vf16 c0B = vzero16(), c1B = vzero16();
        #pragma unroll 2
        for (int ks = 0; ks < 32; ks += 2) {
            {
                const int k0 = ks * 16;
                vhalf8 ah0 = ld_act32(A, lane, 1024, 0,  k0);
                vhalf8 ah1 = ld_act32(A, lane, 1024, 32, k0);
                vhalf8 b   = ld_pack(P2, wid * 32 + ks, lane);
                c0A = MFMA32(ah0, b, c0A);
                c1A = MFMA32(ah1, b, c1A);
            }
            {
                const int k0 = ks * 16 + 16;
                vhalf8 ah0 = ld_act32(A, lane, 1024, 0,  k0);
                vhalf8 ah1 = ld_act32(A, lane, 1024, 32, k0);
                vhalf8 b   = ld_pack(P2, wid * 32 + ks + 1, lane);
                c0B = MFMA32(ah0, b, c0B);
                c1B = MFMA32(ah1, b, c1B);
            }
        }
        g2a0 = c0A + c0B; g2a1 = c1A + c1B;
    }
    __syncthreads();   // B3a: all waves done reading X1
    {
        const int e0 = wid * 32;
        #pragma unroll
        for (int r = 0; r < 16; ++r) {
            const int rr = (r & 3) + 8 * (r >> 2) + 4 * (lane >> 5);
            st_hi(A, rr,      e0 + (lane & 31), 512, gelu_fast(g2a0[r]));
            st_hi(A, rr + 32, e0 + (lane & 31), 512, gelu_fast(g2a1[r]));
        }
    }
    __syncthreads();   // B3b: X2 ready (in [0,32K))

    // ---- GEMM3: X3 = gelu(X2 @ W_l2^T), 64x128, K=256, 16x16x32 ----
    {
        const int e0 = wid * 16;               // wave owns n-tile wid
        vf4 ac[4];                             // m-tiles: rows 16*mt..16*mt+15
        #pragma unroll
        for (int mt = 0; mt < 4; ++mt) ac[mt] = vzero4();
        #pragma unroll 2
        for (int ks = 0; ks < 8; ++ks) {
            const int k0 = ks * 32;
            vhalf8 b = ld_pack(P3, wid * 8 + ks, lane);
            #pragma unroll
            for (int mt = 0; mt < 4; ++mt) {
                vhalf8 ah = ld_act16(A, lane, 512, mt * 16, k0);
                ac[mt] = MFMA16(ah, b, ac[mt]);
            }
        }
        __syncthreads();   // B4a: all waves done reading X2
        #pragma unroll
        for (int mt = 0; mt < 4; ++mt)
            #pragma unroll
            for (int r = 0; r < 4; ++r) {
                const int rr = mt * 16 + ((lane >> 4) << 2) + r;
                sX3[rr * 132 + e0 + (lane & 15)] = gelu_fast(ac[mt][r]);
            }
    }
    __syncthreads();   // B4b: X3 ready

    // ---- layer4 (fp32) + decision + flag: 64 rows x 8 lanes ----
    {
        const int row = tid >> 3;
        const int j   = tid & 7;
        float p = 0.0f;
        #pragma unroll
        for (int t = 0; t < 16; ++t)
            p = fmaf(sX3[row * 132 + j + 8 * t], W_l3[j + 8 * t], p);
        p += __shfl_down(p, 4, 8);
        p += __shfl_down(p, 2, 8);
        p += __shfl_down(p, 1, 8);
        if (j == 0) {
            const float prob = 1.0f / (1.0f + expf(-p));
            const float v    = prob * prev_m[row0 + row];
            const float st   = (v > 0.5f) ? 1.0f : 0.0f;
            const float cm   = st + 1e-10f;
            sM[row] = cm;
            mask_out[row0 + row]  = st;
            currm_out[row0 + row] = cm;
            if (fabsf(v - 0.5f) < BAND) {
                const unsigned int slot = atomicAdd(ctr, 1u);
                list[slot] = row0 + row;
            }
        }
    }
    __syncthreads();   // B5: sM ready

    // ---- epilogue: out = input * curr_m (re-read; L3-resident) ----
    #pragma unroll
    for (int it = 0; it < 16; ++it) {
        const int c = it * NT + tid;           // 8192 float4 = 64 rows x 128
        const int r = c >> 7;
        const int q = (c & 127) << 2;
        const float m = sM[r];
        const float4 v = *(const float4*)&input[(size_t)(row0 + r) * D0 + q];
        float4 o;
        o.x = v.x * m; o.y = v.y * m; o.z = v.z * m; o.w = v.w * m;
        *(float4*)&out[(size_t)(row0 + r) * D0 + q] = o;
    }
}

// ---------------- pass C: exact fp32 recompute of flagged rows --------------
// 16 rows/iter, 512 threads. L1: e=tid (512 exactly). L2: e=tid&255, row-half
// by tid>>8. L3: e=tid&127, row-quad by tid>>7. Full thread utilization,
// broadcast LDS reads, unroll-2 weight prefetch. LDS 88.06 KB -> 1 block/CU.
__global__ __launch_bounds__(512) void fix_rows(
    const float* __restrict__ input, const float* __restrict__ prev_m,
    const float* __restrict__ W_L, const float* __restrict__ W_l1,
    const float* __restrict__ W_l2, const float* __restrict__ W_l3,
    const unsigned int* __restrict__ ctr, const int* __restrict__ list,
    float* __restrict__ out, float* __restrict__ mask_out, float* __restrict__ currm_out)
{
    __shared__ float sx[16][512];
    __shared__ float s1[16][512];
    __shared__ float s2[16][256];
    __shared__ float s3[16][128];
    __shared__ float scm[16];
    const int tid = threadIdx.x;
    const int n = (int)*ctr;

    for (int base = blockIdx.x * 16; base < n; base += gridDim.x * 16) {
        int cnt = n - base;
        if (cnt > 16) cnt = 16;
        __syncthreads();                       // protect prev iteration LDS
        #pragma unroll
        for (int g = 0; g < 16; ++g) {
            if (g < cnt) sx[g][tid] = input[(size_t)list[base + g] * 512 + tid];
            else         sx[g][tid] = 0.0f;
        }
        __syncthreads();
        // L1: e = tid (512 outputs)
        {
            const float4* wr = (const float4*)&W_L[(size_t)tid * 512];
            float a[16];
            #pragma unroll
            for (int g = 0; g < 16; ++g) a[g] = 0.0f;
            #pragma unroll 2
            for (int kq = 0; kq < 128; ++kq) {
                const float4 w = wr[kq];
                #pragma unroll
                for (int g = 0; g < 16; ++g) {
                    const float4 xv = *(const float4*)&sx[g][kq * 4];
                    a[g] = fmaf(xv.x, w.x, a[g]); a[g] = fmaf(xv.y, w.y, a[g]);
                    a[g] = fmaf(xv.z, w.z, a[g]); a[g] = fmaf(xv.w, w.w, a[g]);
                }
            }
            #pragma unroll
            for (int g = 0; g < 16; ++g) s1[g][tid] = gelu_exact(a[g]);
        }
        __syncthreads();
        // L2: e = tid&255, rows [g0, g0+8)
        {
            const int e = tid & 255, g0 = (tid >> 8) * 8;
            const float4* wr = (const float4*)&W_l1[(size_t)e * 512];
            float a[8];
            #pragma unroll
            for (int g = 0; g < 8; ++g) a[g] = 0.0f;
            #pragma unroll 2
            for (int kq = 0; kq < 128; ++kq) {
                const float4 w = wr[kq];
                #pragma unroll
                for (int g = 0; g < 8; ++g) {
                    const float4 xv = *(const float4*)&s1[g0 + g][kq * 4];
                    a[g] = fmaf(xv.x, w.x, a[g]); a[g] = fmaf(xv.y, w.y, a[g]);
                    a[g] = fmaf(xv.z, w.z, a[g]); a[g] = fmaf(xv.w, w.w, a[g]);
                }
            }
            #pragma unroll
            for (int g = 0; g < 8; ++g) s2[g0 + g][e] = gelu_exact(a[g]);
        }
        __syncthreads();
        // L3: e = tid&127, rows [g0, g0+4)
        {
            const int e = tid & 127, g0 = (tid >> 7) * 4;
            const float4* wr = (const float4*)&W_l2[(size_t)e * 256];
            float a[4];
            #pragma unroll
            for (int g = 0; g < 4; ++g) a[g] = 0.0f;
            #pragma unroll 2
            for (int kq = 0; kq < 64; ++kq) {
                const float4 w = wr[kq];
                #pragma unroll
                for (int g = 0; g < 4; ++g) {
                    const float4 xv = *(const float4*)&s2[g0 + g][kq * 4];
                    a[g] = fmaf(xv.x, w.x, a[g]); a[g] = fmaf(xv.y, w.y, a[g]);
                    a[g] = fmaf(xv.z, w.z, a[g]); a[g] = fmaf(xv.w, w.w, a[g]);
                }
            }
            #pragma unroll
            for (int g = 0; g < 4; ++g) s3[g0 + g][e] = gelu_exact(a[g]);
        }
        __syncthreads();
        // L4 + decision: 16 rows x 16 lanes (tid < 256)
        if (tid < 256) {
            const int g = tid >> 4, j = tid & 15;
            float p = 0.0f;
            #pragma unroll
            for (int t = 0; t < 8; ++t)
                p = fmaf(s3[g][j + 16 * t], W_l3[j + 16 * t], p);
            #pragma unroll
            for (int off = 8; off > 0; off >>= 1)
                p += __shfl_down(p, off, 16);
            if (j == 0 && g < cnt) {
                const int row = list[base + g];
                const float prob = 1.0f / (1.0f + expf(-p));
                const float v    = prob * prev_m[row];
                const float st   = (v > 0.5f) ? 1.0f : 0.0f;
                const float cm   = st + 1e-10f;
                mask_out[row]  = st;
                currm_out[row] = cm;
                scm[g] = cm;
            }
        }
        __syncthreads();
        // rewrite out rows
        for (int idx = tid; idx < cnt * 128; idx += 512) {
            const int g = idx >> 7;
            const int q = (idx & 127) << 2;
            const int row = list[base + g];
            const float cm = scm[g];
            const float4 v = *(const float4*)&input[(size_t)row * 512 + q];
            float4 o;
            o.x = v.x * cm; o.y = v.y * cm; o.z = v.z * cm; o.w = v.w * cm;
            *(float4*)&out[(size_t)row * 512 + q] = o;
        }
    }
}

}  // namespace

extern "C" void kernel_launch(void* const* d_in, const int* in_sizes, int n_in,
                              void* d_out, int out_size, void* d_ws, size_t ws_size,
                              hipStream_t stream) {
    const float* input  = (const float*)d_in[0];
    // d_in[1] = attention_mask: unused by the reference computation
    const float* prev_m = (const float*)d_in[2];
    const float* W_L    = (const float*)d_in[3];
    const float* W_l1   = (const float*)d_in[4];
    const float* W_l2   = (const float*)d_in[5];
    const float* W_l3   = (const float*)d_in[6];

    float* out_p   = (float*)d_out;                  // [R, 512]
    float* mask_p  = out_p + (size_t)R_ROWS * D0;    // [R]
    float* currm_p = mask_p + R_ROWS;                // [R]

    // workspace (bytes): ctr @0, list @1024 (256KB), packed fp16 weights after
    char* ws = (char*)d_ws;
    unsigned int* ctr = (unsigned int*)ws;
    int* list = (int*)(ws + 1024);
    char* P1 = ws + 263168;    // 512 KB
    char* P2 = ws + 787456;    // 256 KB
    char* P3 = ws + 1049600;   // 64 KB
    // total ws use: 1115136 bytes

    hipMemsetAsync(ctr, 0, sizeof(unsigned int), stream);
    pack_weights<<<208, 256, 0, stream>>>(W_L, W_l1, W_l2, P1, P2, P3);
    mlp_mfma<<<R_ROWS / TM, NT, 0, stream>>>(input, prev_m, W_l3,
                                             P1, P2, P3,
                                             out_p, mask_p, currm_p, ctr, list);
    fix_rows<<<512, 512, 0, stream>>>(input, prev_m, W_L, W_l1, W_l2, W_l3,
                                      ctr, list, out_p, mask_p, currm_p);
}

// Round 11
// 252.358 us; speedup vs baseline: 2.8774x; 1.0879x over previous
//
#include <hip/hip_runtime.h>
#include <math.h>

// infoFSM mask-scorer MLP — Round 10 (fix: cvt_pkrtz builtin returns __fp16
// vector, incompatible with _Float16 vector type -> use plain casts like R9;
// attempts 1-2 died to infra UnresponsiveContainer): TM=32 no-spill fp16 MFMA.
//
// R9 post-mortem: fp16+band2e-3+new fix pass all correct (absmax=0), main
// 194us, BUT WRITE_SIZE 131.6->189MB = scratch spill: TM=64 needs 64 acc
// VGPRs/lane and launch_bounds(512,4) caps at 128 -> regalloc spilled
// (VGPR_Count 64). R10 right-sizes: TM=32 -> 32 acc/lane, peak ~110 regs,
// zero spill at the same 2-blocks/CU occupancy. LDS 33.4KB. Weight L2
// traffic doubles (R6 proved that dimension non-binding). Even/odd-ks acc
// chains in all GEMMs; 7 barriers.
// Numerics identical to R9: fp16 path, BAND=2e-3 (~22sigma), exact fp32 fix.

namespace {

constexpr int R_ROWS = 128 * 512;   // 65536
constexpr int D0 = 512, D1 = 512, D2 = 256, D3 = 128;
constexpr int TM = 32;              // rows per block (pass B)
constexpr int NT = 512;             // 8 waves

typedef _Float16 vhalf8 __attribute__((ext_vector_type(8)));
typedef _Float16 vhalf4 __attribute__((ext_vector_type(4)));
typedef __attribute__((ext_vector_type(16))) float vf16;
typedef __attribute__((ext_vector_type(4)))  float vf4;

// ---------------- helpers ----------------
__device__ __forceinline__ float gelu_exact(float x) {
    return 0.5f * x * (1.0f + erff(x * 0.70710678118654752440f));
}
// A&S 7.1.26 erf: |abs err| <= 1.5e-7 — far below fp16 path error.
__device__ __forceinline__ float gelu_fast(float x) {
    const float s = fabsf(x) * 0.70710678118654752440f;
    const float t = __builtin_amdgcn_rcpf(fmaf(0.3275911f, s, 1.0f));
    float p = fmaf(1.061405429f, t, -1.453152027f);
    p = fmaf(p, t, 1.421413741f);
    p = fmaf(p, t, -0.284496736f);
    p = fmaf(p, t, 0.254829592f);
    p *= t;
    const float e = __builtin_amdgcn_exp2f(s * s * -1.44269504088896341f);
    float er = fmaf(-p, e, 1.0f);             // erf(|x|/sqrt2)
    er = copysignf(er, x);
    return 0.5f * x * (1.0f + er);
}
__device__ __forceinline__ vf16 vzero16() {
    vf16 v;
    #pragma unroll
    for (int i = 0; i < 16; ++i) v[i] = 0.0f;
    return v;
}
__device__ __forceinline__ vf4 vzero4() {
    vf4 v;
    #pragma unroll
    for (int i = 0; i < 4; ++i) v[i] = 0.0f;
    return v;
}

// LDS activation tiles: [row][k] fp16, XOR-swizzle bits 4..6.
__device__ __forceinline__ int swz_off(int row, int colElem, int pitchB) {
    return (row * pitchB + colElem * 2) ^ ((row & 7) << 4);
}
// 32x32 A-fragment read: row = lane&31, k = k0 + (lane>>5)*8
__device__ __forceinline__ vhalf8 ld_act32(const char* base, int lane, int pitchB,
                                           int k0) {
    const int row = lane & 31;
    const int k = k0 + ((lane >> 5) << 3);
    return *(const vhalf8*)(base + swz_off(row, k, pitchB));
}
// 16x16 A-fragment read: row = row0 + lane&15, k = k0 + (lane>>4)*8
__device__ __forceinline__ vhalf8 ld_act16(const char* base, int lane, int pitchB,
                                           int row0, int k0) {
    const int row = row0 + (lane & 15);
    const int k = k0 + ((lane >> 4) << 3);
    return *(const vhalf8*)(base + swz_off(row, k, pitchB));
}
// packed weight fragment: P + blk*1024B + lane*16B
__device__ __forceinline__ vhalf8 ld_pack(const char* __restrict__ P,
                                          int blk, int lane) {
    return *(const vhalf8*)(P + (((size_t)blk) << 10) + (lane << 4));
}
__device__ __forceinline__ void st_hi(char* base, int row, int col, int pitchB, float x) {
    *(_Float16*)(base + swz_off(row, col, pitchB)) = (_Float16)x;
}

#define MFMA32(a, b, c) __builtin_amdgcn_mfma_f32_32x32x16_f16((a), (b), (c), 0, 0, 0)
#define MFMA16(a, b, c) __builtin_amdgcn_mfma_f32_16x16x32_f16((a), (b), (c), 0, 0, 0)

constexpr float BAND = 2e-3f;   // on v = prob*prev_m; ~22x RMS fp16-path err

// ---------------- pass A: pack fp16 weights into fragment order -------------
// P1: GEMM1 (32x32x16): blk=nt*32+ks, nt=0..15; lane l -> W_L[nt*32+(l&31)][ks*16+(l>>5)*8+j]
// P2: GEMM2: blk=nt*32+ks, nt=0..7 (W_l1)
// P3: GEMM3 (16x16x32): blk=nt*8+ks, nt=0..7; lane l -> W_l2[nt*16+(l&15)][ks*32+(l>>4)*8+j]
__global__ __launch_bounds__(256) void pack_weights(
    const float* __restrict__ W_L, const float* __restrict__ W_l1,
    const float* __restrict__ W_l2,
    char* __restrict__ P1, char* __restrict__ P2, char* __restrict__ P3)
{
    const int g = blockIdx.x * 256 + threadIdx.x;   // 53248 threads total
    const float* src;
    char* dst;
    int e, k, K, blk, lane;
    if (g < 32768) {
        lane = g & 63;
        const int ks = (g >> 6) & 31, nt = g >> 11;
        src = W_L; K = 512; dst = P1;
        e = nt * 32 + (lane & 31);
        k = ks * 16 + ((lane >> 5) << 3);
        blk = nt * 32 + ks;
    } else if (g < 49152) {
        const int h = g - 32768;
        lane = h & 63;
        const int ks = (h >> 6) & 31, nt = h >> 11;
        src = W_l1; K = 512; dst = P2;
        e = nt * 32 + (lane & 31);
        k = ks * 16 + ((lane >> 5) << 3);
        blk = nt * 32 + ks;
    } else {
        const int h = g - 49152;
        lane = h & 63;
        const int ks = (h >> 6) & 7, nt = h >> 9;
        src = W_l2; K = 256; dst = P3;
        e = nt * 16 + (lane & 15);
        k = ks * 32 + ((lane >> 4) << 3);
        blk = nt * 8 + ks;
    }
    const float4 v0 = *(const float4*)&src[(size_t)e * K + k];
    const float4 v1 = *(const float4*)&src[(size_t)e * K + k + 4];
    const float xs[8] = {v0.x, v0.y, v0.z, v0.w, v1.x, v1.y, v1.z, v1.w};
    vhalf8 hv;
    #pragma unroll
    for (int j = 0; j < 8; ++j) hv[j] = (_Float16)xs[j];
    *(vhalf8*)(dst + (((size_t)blk) << 10) + lane * 16) = hv;
}

// ---------------- pass B: fused fp16 MFMA MLP, TM=32, 33.4KB LDS ------------
// LDS overlay (bytes):
//   stage A:  A  [0,32K)  f16 [32][512] pitch 1024
//   GEMM1 ep: X1 [0,32K)  f16 [32][512] pitch 1024  (A dead, B2a)
//   GEMM2 ep: X2 [0,16K)  f16 [32][256] pitch 512   (X1 dead, B3a)
//   GEMM3 ep: X3 [16K, 16K+16896) f32 [32][132]     (X1 upper dead; disjoint X2)
//   sM at [33280, 33408)
constexpr int SMEM_BYTES = 33280 + 128;

__global__ __launch_bounds__(NT, 4) void mlp_mfma(
    const float* __restrict__ input, const float* __restrict__ prev_m,
    const float* __restrict__ W_l3,
    const char* __restrict__ P1, const char* __restrict__ P2,
    const char* __restrict__ P3,
    float* __restrict__ out, float* __restrict__ mask_out, float* __restrict__ currm_out,
    unsigned int* __restrict__ ctr, int* __restrict__ list)
{
    __shared__ __attribute__((aligned(16))) char smem[SMEM_BYTES];
    char* A   = smem;                         // then X1, then X2 (overlaid)
    float* sX3 = (float*)(smem + 16384);      // [32][132] f32
    float* sM  = (float*)(smem + 33280);      // [32]

    const int tid  = threadIdx.x;
    const int lane = tid & 63;
    const int wid  = tid >> 6;
    const int row0 = blockIdx.x * TM;

    // ---- stage A: 32 input rows -> fp16, swizzled ----
    #pragma unroll
    for (int i = 0; i < 8; ++i) {
        const int c  = i * NT + tid;           // 0..4095 float4-chunks
        const int r  = c >> 7;                 // 0..31
        const int kq = (c & 127) << 2;
        const float4 v = *(const float4*)&input[(size_t)(row0 + r) * D0 + kq];
        vhalf4 hv = {(_Float16)v.x, (_Float16)v.y, (_Float16)v.z, (_Float16)v.w};
        const int off = (r * 1024 + kq * 2) ^ ((r & 7) << 4);   // 8B-aligned
        *(vhalf4*)(A + off) = hv;
    }
    __syncthreads();   // B1: A staged

    // ---- GEMM1: X1 = gelu(A @ W_L^T), 32x512, K=512, 32x32x16 ----
    // wave owns n-tiles nt0, nt0+1; even/odd-ks chains -> 4 independent accs.
    vf16 g1a0, g1a1;
    {
        const int nt0 = wid * 2;
        vf16 aE0 = vzero16(), aE1 = vzero16();
        vf16 aO0 = vzero16(), aO1 = vzero16();
        #pragma unroll 2
        for (int ks = 0; ks < 32; ks += 2) {
            {
                const int k0 = ks * 16;
                vhalf8 ah = ld_act32(A, lane, 1024, k0);
                vhalf8 b0 = ld_pack(P1, nt0 * 32 + ks, lane);
                vhalf8 b1 = ld_pack(P1, (nt0 + 1) * 32 + ks, lane);
                aE0 = MFMA32(ah, b0, aE0);
                aE1 = MFMA32(ah, b1, aE1);
            }
            {
                const int k0 = ks * 16 + 16;
                vhalf8 ah = ld_act32(A, lane, 1024, k0);
                vhalf8 b0 = ld_pack(P1, nt0 * 32 + ks + 1, lane);
                vhalf8 b1 = ld_pack(P1, (nt0 + 1) * 32 + ks + 1, lane);
                aO0 = MFMA32(ah, b0, aO0);
                aO1 = MFMA32(ah, b1, aO1);
            }
        }
        g1a0 = aE0 + aO0; g1a1 = aE1 + aO1;
    }
    __syncthreads();   // B2a: all waves done reading A
    {
        const int e0 = wid * 64;
        #pragma unroll
        for (int r = 0; r < 16; ++r) {
            const int rr = (r & 3) + 8 * (r >> 2) + 4 * (lane >> 5);
            st_hi(A, rr, e0 + (lane & 31),      1024, gelu_fast(g1a0[r]));
            st_hi(A, rr, e0 + 32 + (lane & 31), 1024, gelu_fast(g1a1[r]));
        }
    }
    __syncthreads();   // B2b: X1 ready (in A's region)

    // ---- GEMM2: X2 = gelu(X1 @ W_l1^T), 32x256, K=512, 32x32x16 ----
    vf16 g2a;
    {
        vf16 cE = vzero16(), cO = vzero16();
        #pragma unroll 2
        for (int ks = 0; ks < 32; ks += 2) {
            {
                const int k0 = ks * 16;
                vhalf8 ah = ld_act32(A, lane, 1024, k0);
                vhalf8 b  = ld_pack(P2, wid * 32 + ks, lane);
                cE = MFMA32(ah, b, cE);
            }
            {
                const int k0 = ks * 16 + 16;
                vhalf8 ah = ld_act32(A, lane, 1024, k0);
                vhalf8 b  = ld_pack(P2, wid * 32 + ks + 1, lane);
                cO = MFMA32(ah, b, cO);
            }
        }
        g2a = cE + cO;
    }
    __syncthreads();   // B3a: all waves done reading X1
    {
        const int e0 = wid * 32;
        #pragma unroll
        for (int r = 0; r < 16; ++r) {
            const int rr = (r & 3) + 8 * (r >> 2) + 4 * (lane >> 5);
            st_hi(A, rr, e0 + (lane & 31), 512, gelu_fast(g2a[r]));
        }
    }
    __syncthreads();   // B3b: X2 ready (in [0,16K))

    // ---- GEMM3: X3 = gelu(X2 @ W_l2^T), 32x128, K=256, 16x16x32 ----
    {
        const int e0 = wid * 16;               // wave owns n-tile wid
        vf4 a0E = vzero4(), a1E = vzero4();    // m-tiles rows 0..15 / 16..31
        vf4 a0O = vzero4(), a1O = vzero4();
        #pragma unroll 2
        for (int ks = 0; ks < 8; ks += 2) {
            {
                const int k0 = ks * 32;
                vhalf8 b  = ld_pack(P3, wid * 8 + ks, lane);
                vhalf8 a0 = ld_act16(A, lane, 512, 0,  k0);
                vhalf8 a1 = ld_act16(A, lane, 512, 16, k0);
                a0E = MFMA16(a0, b, a0E);
                a1E = MFMA16(a1, b, a1E);
            }
            {
                const int k0 = ks * 32 + 32;
                vhalf8 b  = ld_pack(P3, wid * 8 + ks + 1, lane);
                vhalf8 a0 = ld_act16(A, lane, 512, 0,  k0);
                vhalf8 a1 = ld_act16(A, lane, 512, 16, k0);
                a0O = MFMA16(a0, b, a0O);
                a1O = MFMA16(a1, b, a1O);
            }
        }
        const vf4 ac0 = a0E + a0O;
        const vf4 ac1 = a1E + a1O;
        // X3 at [16K,33K): disjoint from X2 [0,16K); overlays dead X1 upper.
        #pragma unroll
        for (int r = 0; r < 4; ++r) {
            const int rr = ((lane >> 4) << 2) + r;
            sX3[rr * 132 + e0 + (lane & 15)]        = gelu_fast(ac0[r]);
            sX3[(rr + 16) * 132 + e0 + (lane & 15)] = gelu_fast(ac1[r]);
        }
    }
    __syncthreads();   // B4: X3 ready

    // ---- layer4 (fp32) + decision + flag: 32 rows x 16 lanes ----
    {
        const int row = tid >> 4;
        const int j   = tid & 15;
        float p = 0.0f;
        #pragma unroll
        for (int t = 0; t < 8; ++t)
            p = fmaf(sX3[row * 132 + j + 16 * t], W_l3[j + 16 * t], p);
        #pragma unroll
        for (int off = 8; off > 0; off >>= 1)
            p += __shfl_down(p, off, 16);
        if (j == 0) {
            const float prob = 1.0f / (1.0f + expf(-p));
            const float v    = prob * prev_m[row0 + row];
            const float st   = (v > 0.5f) ? 1.0f : 0.0f;
            const float cm   = st + 1e-10f;
            sM[row] = cm;
            mask_out[row0 + row]  = st;
            currm_out[row0 + row] = cm;
            if (fabsf(v - 0.5f) < BAND) {
                const unsigned int slot = atomicAdd(ctr, 1u);
                list[slot] = row0 + row;
            }
        }
    }
    __syncthreads();   // B5: sM ready

    // ---- epilogue: out = input * curr_m (re-read; L3-resident) ----
    #pragma unroll
    for (int it = 0; it < 8; ++it) {
        const int c = it * NT + tid;           // 4096 float4 = 32 rows x 128
        const int r = c >> 7;
        const int q = (c & 127) << 2;
        const float m = sM[r];
        const float4 v = *(const float4*)&input[(size_t)(row0 + r) * D0 + q];
        float4 o;
        o.x = v.x * m; o.y = v.y * m; o.z = v.z * m; o.w = v.w * m;
        *(float4*)&out[(size_t)(row0 + r) * D0 + q] = o;
    }
}

// ---------------- pass C: exact fp32 recompute of flagged rows --------------
// 16 rows/iter, 512 threads, broadcast LDS reads, unroll-2 weight prefetch.
__global__ __launch_bounds__(512) void fix_rows(
    const float* __restrict__ input, const float* __restrict__ prev_m,
    const float* __restrict__ W_L, const float* __restrict__ W_l1,
    const float* __restrict__ W_l2, const float* __restrict__ W_l3,
    const unsigned int* __restrict__ ctr, const int* __restrict__ list,
    float* __restrict__ out, float* __restrict__ mask_out, float* __restrict__ currm_out)
{
    __shared__ float sx[16][512];
    __shared__ float s1[16][512];
    __shared__ float s2[16][256];
    __shared__ float s3[16][128];
    __shared__ float scm[16];
    const int tid = threadIdx.x;
    const int n = (int)*ctr;

    for (int base = blockIdx.x * 16; base < n; base += gridDim.x * 16) {
        int cnt = n - base;
        if (cnt > 16) cnt = 16;
        __syncthreads();                       // protect prev iteration LDS
        #pragma unroll
        for (int g = 0; g < 16; ++g) {
            if (g < cnt) sx[g][tid] = input[(size_t)list[base + g] * 512 + tid];
            else         sx[g][tid] = 0.0f;
        }
        __syncthreads();
        // L1: e = tid (512 outputs)
        {
            const float4* wr = (const float4*)&W_L[(size_t)tid * 512];
            float a[16];
            #pragma unroll
            for (int g = 0; g < 16; ++g) a[g] = 0.0f;
            #pragma unroll 2
            for (int kq = 0; kq < 128; ++kq) {
                const float4 w = wr[kq];
                #pragma unroll
                for (int g = 0; g < 16; ++g) {
                    const float4 xv = *(const float4*)&sx[g][kq * 4];
                    a[g] = fmaf(xv.x, w.x, a[g]); a[g] = fmaf(xv.y, w.y, a[g]);
                    a[g] = fmaf(xv.z, w.z, a[g]); a[g] = fmaf(xv.w, w.w, a[g]);
                }
            }
            #pragma unroll
            for (int g = 0; g < 16; ++g) s1[g][tid] = gelu_exact(a[g]);
        }
        __syncthreads();
        // L2: e = tid&255, rows [g0, g0+8)
        {
            const int e = tid & 255, g0 = (tid >> 8) * 8;
            const float4* wr = (const float4*)&W_l1[(size_t)e * 512];
            float a[8];
            #pragma unroll
            for (int g = 0; g < 8; ++g) a[g] = 0.0f;
            #pragma unroll 2
            for (int kq = 0; kq < 128; ++kq) {
                const float4 w = wr[kq];
                #pragma unroll
                for (int g = 0; g < 8; ++g) {
                    const float4 xv = *(const float4*)&s1[g0 + g][kq * 4];
                    a[g] = fmaf(xv.x, w.x, a[g]); a[g] = fmaf(xv.y, w.y, a[g]);
                    a[g] = fmaf(xv.z, w.z, a[g]); a[g] = fmaf(xv.w, w.w, a[g]);
                }
            }
            #pragma unroll
            for (int g = 0; g < 8; ++g) s2[g0 + g][e] = gelu_exact(a[g]);
        }
        __syncthreads();
        // L3: e = tid&127, rows [g0, g0+4)
        {
            const int e = tid & 127, g0 = (tid >> 7) * 4;
            const float4* wr = (const float4*)&W_l2[(size_t)e * 256];
            float a[4];
            #pragma unroll
            for (int g = 0; g < 4; ++g) a[g] = 0.0f;
            #pragma unroll 2
            for (int kq = 0; kq < 64; ++kq) {
                const float4 w = wr[kq];
                #pragma unroll
                for (int g = 0; g < 4; ++g) {
                    const float4 xv = *(const float4*)&s2[g0 + g][kq * 4];
                    a[g] = fmaf(xv.x, w.x, a[g]); a[g] = fmaf(xv.y, w.y, a[g]);
                    a[g] = fmaf(xv.z, w.z, a[g]); a[g] = fmaf(xv.w, w.w, a[g]);
                }
            }
            #pragma unroll
            for (int g = 0; g < 4; ++g) s3[g0 + g][e] = gelu_exact(a[g]);
        }
        __syncthreads();
        // L4 + decision: 16 rows x 16 lanes (tid < 256)
        if (tid < 256) {
            const int g = tid >> 4, j = tid & 15;
            float p = 0.0f;
            #pragma unroll
            for (int t = 0; t < 8; ++t)
                p = fmaf(s3[g][j + 16 * t], W_l3[j + 16 * t], p);
            #pragma unroll
            for (int off = 8; off > 0; off >>= 1)
                p += __shfl_down(p, off, 16);
            if (j == 0 && g < cnt) {
                const int row = list[base + g];
                const float prob = 1.0f / (1.0f + expf(-p));
                const float v    = prob * prev_m[row];
                const float st   = (v > 0.5f) ? 1.0f : 0.0f;
                const float cm   = st + 1e-10f;
                mask_out[row]  = st;
                currm_out[row] = cm;
                scm[g] = cm;
            }
        }
        __syncthreads();
        // rewrite out rows
        for (int idx = tid; idx < cnt * 128; idx += 512) {
            const int g = idx >> 7;
            const int q = (idx & 127) << 2;
            const int row = list[base + g];
            const float cm = scm[g];
            const float4 v = *(const float4*)&input[(size_t)row * 512 + q];
            float4 o;
            o.x = v.x * cm; o.y = v.y * cm; o.z = v.z * cm; o.w = v.w * cm;
            *(float4*)&out[(size_t)row * 512 + q] = o;
        }
    }
}

}  // namespace

extern "C" void kernel_launch(void* const* d_in, const int* in_sizes, int n_in,
                              void* d_out, int out_size, void* d_ws, size_t ws_size,
                              hipStream_t stream) {
    const float* input  = (const float*)d_in[0];
    // d_in[1] = attention_mask: unused by the reference computation
    const float* prev_m = (const float*)d_in[2];
    const float* W_L    = (const float*)d_in[3];
    const float* W_l1   = (const float*)d_in[4];
    const float* W_l2   = (const float*)d_in[5];
    const float* W_l3   = (const float*)d_in[6];

    float* out_p   = (float*)d_out;                  // [R, 512]
    float* mask_p  = out_p + (size_t)R_ROWS * D0;    // [R]
    float* currm_p = mask_p + R_ROWS;                // [R]

    // workspace (bytes): ctr @0, list @1024 (256KB), packed fp16 weights after
    char* ws = (char*)d_ws;
    unsigned int* ctr = (unsigned int*)ws;
    int* list = (int*)(ws + 1024);
    char* P1 = ws + 263168;    // 512 KB
    char* P2 = ws + 787456;    // 256 KB
    char* P3 = ws + 1049600;   // 64 KB
    // total ws use: 1115136 bytes

    (void)hipMemsetAsync(ctr, 0, sizeof(unsigned int), stream);
    pack_weights<<<208, 256, 0, stream>>>(W_L, W_l1, W_l2, P1, P2, P3);
    mlp_mfma<<<R_ROWS / TM, NT, 0, stream>>>(input, prev_m, W_l3,
                                             P1, P2, P3,
                                             out_p, mask_p, currm_p, ctr, list);
    fix_rows<<<512, 512, 0, stream>>>(input, prev_m, W_L, W_l1, W_l2, W_l3,
                                      ctr, list, out_p, mask_p, currm_p);
}